// Round 2
// 706.701 us; speedup vs baseline: 1.2491x; 1.2491x over previous
//
#include <hip/hip_runtime.h>
#include <math.h>
#include <stdint.h>
#include <stddef.h>

#define HID 2048
#define NH 16
#define NKV 4
#define HD 128
#define GROUPS (NH / NKV)
#define BATCH 2
#define SEQ 2048

#define N_HS  8388608ull
#define N_Q   8388608ull
#define N_KV  2097152ull
#define N_WQ  4194304ull
#define N_WKV 1048576ull
#define N_WO  4194304ull

typedef __attribute__((ext_vector_type(8))) short bf16x8;
typedef __attribute__((ext_vector_type(4))) float f32x4;

__device__ inline float quantv(float x, float s) {
  float q = rintf(x / s);
  return fminf(fmaxf(q, -128.0f), 127.0f);
}

__device__ inline float slot_scale(const unsigned int* slots, int i) {
  return fmaxf(__uint_as_float(slots[i]) / 127.0f, 1e-8f);
}

__device__ inline unsigned short f2bf(float x) {
  return (unsigned short)(__float_as_uint(x) >> 16);
}

__device__ inline float amax4(float4 v) {
  return fmaxf(fmaxf(fabsf(v.x), fabsf(v.y)), fmaxf(fabsf(v.z), fabsf(v.w)));
}

__device__ inline void block_amax_atomic(float m, unsigned int* slot) {
  __shared__ float red[256];
  red[threadIdx.x] = m;
  __syncthreads();
  for (int o = 128; o > 0; o >>= 1) {
    if (threadIdx.x < o) red[threadIdx.x] = fmaxf(red[threadIdx.x], red[threadIdx.x + o]);
    __syncthreads();
  }
  if (threadIdx.x == 0) atomicMax(slot, __float_as_uint(red[0]));
}

// async global -> LDS, 16B per lane (dest = wave-uniform base + lane*16)
__device__ __forceinline__ void gload_lds16(const void* g, void* l) {
  __builtin_amdgcn_global_load_lds((const __attribute__((address_space(1))) unsigned int*)g,
                                   (__attribute__((address_space(3))) unsigned int*)l, 16, 0, 0);
}

// ---------------- fused absmax over the 5 input tensors ----------------
__global__ __launch_bounds__(256) void absmax5_k(const float* __restrict__ a0,
                                                 const float* __restrict__ a1,
                                                 const float* __restrict__ a2,
                                                 const float* __restrict__ a3,
                                                 const float* __restrict__ a4,
                                                 unsigned int* __restrict__ slots) {
  const int t = blockIdx.y;
  const float* x = t == 0 ? a0 : t == 1 ? a1 : t == 2 ? a2 : t == 3 ? a3 : a4;
  const size_t n4 = (t == 0 ? N_HS : t == 1 ? N_WQ : t == 2 ? N_WKV : t == 3 ? N_WKV : N_WO) / 4;
  const float4* xp = (const float4*)x;
  float m = 0.0f;
  for (size_t i = (size_t)blockIdx.x * 256 + threadIdx.x; i < n4; i += (size_t)gridDim.x * 256)
    m = fmaxf(m, amax4(xp[i]));
  block_amax_atomic(m, slots + t);
}

// ---------------- fused quantize over 5 tensors ----------------
__global__ __launch_bounds__(256) void quant5_k(const float* __restrict__ a0,
                                                const float* __restrict__ a1,
                                                const float* __restrict__ a2,
                                                const float* __restrict__ a3,
                                                const float* __restrict__ a4,
                                                const unsigned int* __restrict__ slots,
                                                unsigned short* __restrict__ o0,
                                                unsigned short* __restrict__ o1,
                                                unsigned short* __restrict__ o2,
                                                unsigned short* __restrict__ o3,
                                                unsigned short* __restrict__ o4) {
  const int t = blockIdx.y;
  const float* x = t == 0 ? a0 : t == 1 ? a1 : t == 2 ? a2 : t == 3 ? a3 : a4;
  unsigned short* o = t == 0 ? o0 : t == 1 ? o1 : t == 2 ? o2 : t == 3 ? o3 : o4;
  const size_t n4 = (t == 0 ? N_HS : t == 1 ? N_WQ : t == 2 ? N_WKV : t == 3 ? N_WKV : N_WO) / 4;
  const float s = fmaxf(__uint_as_float(slots[t]) / 127.0f, 1e-8f);
  const float4* xp = (const float4*)x;
  ushort4* op = (ushort4*)o;
  for (size_t i = (size_t)blockIdx.x * 256 + threadIdx.x; i < n4; i += (size_t)gridDim.x * 256) {
    float4 v = xp[i];
    ushort4 r;
    r.x = f2bf(quantv(v.x, s));
    r.y = f2bf(quantv(v.y, s));
    r.z = f2bf(quantv(v.z, s));
    r.w = f2bf(quantv(v.w, s));
    op[i] = r;
  }
}

// ---------------- fused quantize q/k ----------------
__global__ __launch_bounds__(256) void quant2_k(const float* __restrict__ a0,
                                                const float* __restrict__ a1,
                                                const unsigned int* __restrict__ slots,
                                                unsigned short* __restrict__ o0,
                                                unsigned short* __restrict__ o1) {
  const int t = blockIdx.y;
  const float* x = t == 0 ? a0 : a1;
  unsigned short* o = t == 0 ? o0 : o1;
  const size_t n4 = (t == 0 ? N_Q : N_KV) / 4;
  const float s = fmaxf(__uint_as_float(slots[5 + t]) / 127.0f, 1e-8f);
  const float4* xp = (const float4*)x;
  ushort4* op = (ushort4*)o;
  for (size_t i = (size_t)blockIdx.x * 256 + threadIdx.x; i < n4; i += (size_t)gridDim.x * 256) {
    float4 v = xp[i];
    ushort4 r;
    r.x = f2bf(quantv(v.x, s));
    r.y = f2bf(quantv(v.y, s));
    r.z = f2bf(quantv(v.z, s));
    r.w = f2bf(quantv(v.w, s));
    op[i] = r;
  }
}

__global__ __launch_bounds__(256) void quant1_k(const float* __restrict__ x, size_t n4,
                                                const unsigned int* __restrict__ slot,
                                                unsigned short* __restrict__ out) {
  const float s = fmaxf(__uint_as_float(*slot) / 127.0f, 1e-8f);
  const float4* xp = (const float4*)x;
  ushort4* op = (ushort4*)out;
  for (size_t i = (size_t)blockIdx.x * 256 + threadIdx.x; i < n4; i += (size_t)gridDim.x * 256) {
    float4 v = xp[i];
    ushort4 r;
    r.x = f2bf(quantv(v.x, s));
    r.y = f2bf(quantv(v.y, s));
    r.z = f2bf(quantv(v.z, s));
    r.w = f2bf(quantv(v.w, s));
    op[i] = r;
  }
}

// ---------------- V: quantize + transpose to [b][hk][d][s] ----------------
__global__ __launch_bounds__(256) void vtq_k(const float* __restrict__ vbuf,
                                             const unsigned int* __restrict__ slots,
                                             unsigned short* __restrict__ vbt) {
  __shared__ unsigned short L[128 * 72];
  const int tid = threadIdx.x;
  const int s0 = blockIdx.x * 64;
  const int hk = blockIdx.y;
  const int b = blockIdx.z;
  const float s = fmaxf(__uint_as_float(slots[7]) / 127.0f, 1e-8f);
#pragma unroll
  for (int it = 0; it < 8; it++) {
    int idx = tid + it * 256;
    int sl = idx >> 5, c4 = idx & 31;
    float4 v = ((const float4*)(vbuf + ((size_t)(b * SEQ + s0 + sl) * NKV + hk) * HD))[c4];
    L[(c4 * 4 + 0) * 72 + sl] = f2bf(quantv(v.x, s));
    L[(c4 * 4 + 1) * 72 + sl] = f2bf(quantv(v.y, s));
    L[(c4 * 4 + 2) * 72 + sl] = f2bf(quantv(v.z, s));
    L[(c4 * 4 + 3) * 72 + sl] = f2bf(quantv(v.w, s));
  }
  __syncthreads();
  const size_t obase = ((size_t)(b * NKV + hk)) * HD * SEQ + s0;
#pragma unroll
  for (int it = 0; it < 4; it++) {
    int idx = tid + it * 256;
    int d = idx >> 3, sc = idx & 7;
    *(bf16x8*)(vbt + obase + (size_t)d * SEQ + sc * 8) = *(const bf16x8*)(&L[d * 72 + sc * 8]);
  }
}

// ---------------- MFMA GEMM body: global_load_lds double-buffer (T3 2-phase) -------------
// One barrier per K-step; staging loads stay in flight across the MFMA phase and are
// drained by the vmcnt(0) the compiler emits inside __syncthreads().
__device__ __forceinline__ void gemm_body(const unsigned short* __restrict__ A,
                                          const unsigned short* __restrict__ B,
                                          float* __restrict__ C, int N, int K, int m0, int n0,
                                          float sc, int amax_slot, unsigned int* slots) {
  __shared__ unsigned short As[2][128 * 32];
  __shared__ unsigned short Bs[2][128 * 32];
  const int tid = threadIdx.x;
  const int wave = tid >> 6, lane = tid & 63;
  const int l16 = lane & 15, quad = lane >> 4;
  const int wm = (wave & 1) * 64, wn = (wave >> 1) * 64;

  f32x4 acc[4][4];
#pragma unroll
  for (int i = 0; i < 4; i++)
#pragma unroll
    for (int j = 0; j < 4; j++) acc[i][j] = (f32x4){0.f, 0.f, 0.f, 0.f};

  // LDS layout is linear in c = it*256 + tid (byte offset c*16) -> matches the
  // wave-uniform-base + lane*16 write pattern of global_load_lds.
  auto STAGE = [&](int buf, int kt) {
#pragma unroll
    for (int it = 0; it < 2; it++) {
      int c = it * 256 + tid;
      int r = c >> 2, kc = (c & 3) * 8;
      gload_lds16(A + (size_t)(m0 + r) * K + kt + kc, &As[buf][(it * 256 + wave * 64) * 8]);
      gload_lds16(B + (size_t)(n0 + r) * K + kt + kc, &Bs[buf][(it * 256 + wave * 64) * 8]);
    }
  };

  STAGE(0, 0);
  int cur = 0;
  const int nk = K / 32;
  for (int t = 0; t < nk; t++) {
    __syncthreads();  // drains vmcnt: buf[cur] ready; prev readers done with buf[cur^1]
    if (t + 1 < nk) STAGE(cur ^ 1, (t + 1) * 32);
    bf16x8 af[4], bq[4];
#pragma unroll
    for (int i = 0; i < 4; i++)
      af[i] = *(const bf16x8*)(&As[cur][(wm + i * 16 + l16) * 32 + quad * 8]);
#pragma unroll
    for (int j = 0; j < 4; j++)
      bq[j] = *(const bf16x8*)(&Bs[cur][(wn + j * 16 + l16) * 32 + quad * 8]);
#pragma unroll
    for (int i = 0; i < 4; i++)
#pragma unroll
      for (int j = 0; j < 4; j++)
        acc[i][j] = __builtin_amdgcn_mfma_f32_16x16x32_bf16(af[i], bq[j], acc[i][j], 0, 0, 0);
    cur ^= 1;
  }

  float am = 0.0f;
#pragma unroll
  for (int i = 0; i < 4; i++)
#pragma unroll
    for (int j = 0; j < 4; j++)
#pragma unroll
      for (int r = 0; r < 4; r++) {
        int row = m0 + wm + i * 16 + quad * 4 + r;
        int col = n0 + wn + j * 16 + l16;
        float v = acc[i][j][r] * sc;
        C[(size_t)row * N + col] = v;
        am = fmaxf(am, fabsf(v));
      }
  if (amax_slot >= 0) {
    __syncthreads();
    float* red = (float*)As;
    red[tid] = am;
    __syncthreads();
    for (int o = 128; o > 0; o >>= 1) {
      if (tid < o) red[tid] = fmaxf(red[tid], red[tid + o]);
      __syncthreads();
    }
    if (tid == 0) atomicMax(slots + amax_slot, __float_as_uint(red[0]));
  }
}

// Fused Q/K/V projection: shared A, per-block weight select.
// 24 n-tiles x 32 m-tiles = 768 blocks (3/CU) vs 512+128+128 separate (K/V left half the chip idle).
__global__ __launch_bounds__(256) void gemm_qkv_k(const unsigned short* __restrict__ A,
                                                  const unsigned short* __restrict__ Bq,
                                                  const unsigned short* __restrict__ Bk,
                                                  const unsigned short* __restrict__ Bv,
                                                  float* __restrict__ Cq, float* __restrict__ Ck,
                                                  float* __restrict__ Cv,
                                                  unsigned int* __restrict__ slots) {
  const int nt = blockIdx.x, m0 = blockIdx.y * 128;
  const unsigned short* B;
  float* C;
  int N, n0, ib, amx;
  if (nt < 16) {
    B = Bq; C = Cq; N = 2048; n0 = nt * 128; ib = 1; amx = -1;
  } else if (nt < 20) {
    B = Bk; C = Ck; N = 512; n0 = (nt - 16) * 128; ib = 2; amx = -1;
  } else {
    B = Bv; C = Cv; N = 512; n0 = (nt - 20) * 128; ib = 3; amx = 7;
  }
  const float sc = slot_scale(slots, 0) * slot_scale(slots, ib);
  gemm_body(A, B, C, N, HID, m0, n0, sc, amx, slots);
}

__global__ __launch_bounds__(256) void gemm_o_k(const unsigned short* __restrict__ A,
                                                const unsigned short* __restrict__ B,
                                                float* __restrict__ C,
                                                unsigned int* __restrict__ slots) {
  const float sc = slot_scale(slots, 8) * slot_scale(slots, 4);
  gemm_body(A, B, C, HID, NH * HD, blockIdx.y * 128, blockIdx.x * 128, sc, -1, slots);
}

// ---------------- RoPE in-place + absmax ----------------
__global__ __launch_bounds__(256) void rope_kernel(float* __restrict__ t, int nh,
                                                   unsigned int* __restrict__ slot) {
  size_t idx = (size_t)blockIdx.x * 256 + threadIdx.x;
  size_t total = (size_t)BATCH * SEQ * nh * (HD / 2);
  float am = 0.0f;
  if (idx < total) {
    int i = (int)(idx & 63);
    int h = (int)((idx >> 6) % nh);
    int s = (int)((idx / (64ull * nh)) % SEQ);
    int b = (int)(idx / (64ull * nh * SEQ));
    size_t base = ((size_t)(b * SEQ + s) * nh + h) * HD;
    float inv = 1.0f / powf(10000.0f, (float)(2 * i) * (1.0f / 128.0f));
    float fr = (float)s * inv;
    float c = cosf(fr), sn = sinf(fr);
    float x1 = t[base + i], x2 = t[base + i + 64];
    float r1 = x1 * c - x2 * sn;
    float r2 = x2 * c + x1 * sn;
    t[base + i] = r1;
    t[base + i + 64] = r2;
    am = fmaxf(fabsf(r1), fabsf(r2));
  }
  block_amax_atomic(am, slot);
}

// ---------------- MFMA paired-tile two-pass causal attention ----------------
#define TK 64
#define KS_STRIDE (HD + 8)
#define VT_STRIDE (TK + 8)
#define PS_STRIDE (TK + 8)

__device__ __forceinline__ void ldK(bf16x8 r[4], const unsigned short* kb, int b, int hk,
                                    int j0, int tid) {
#pragma unroll
  for (int it = 0; it < 4; it++) {
    int c2 = tid + it * 256;
    int rr = c2 >> 4, c = c2 & 15;
    r[it] = *(const bf16x8*)(kb + ((size_t)(b * SEQ + j0 + rr) * NKV + hk) * HD + c * 8);
  }
}
__device__ __forceinline__ void stK(unsigned short* Ks, const bf16x8 r[4], int tid) {
#pragma unroll
  for (int it = 0; it < 4; it++) {
    int c2 = tid + it * 256;
    int rr = c2 >> 4, c = c2 & 15;
    *(bf16x8*)(&Ks[rr * KS_STRIDE + c * 8]) = r[it];
  }
}
__device__ __forceinline__ void ldV(bf16x8 r[4], const unsigned short* vbt, size_t vbase,
                                    int j0, int tid) {
#pragma unroll
  for (int it = 0; it < 4; it++) {
    int idx = tid + it * 256;
    int d = idx >> 3, sc = idx & 7;
    r[it] = *(const bf16x8*)(vbt + vbase + (size_t)d * SEQ + j0 + sc * 8);
  }
}
__device__ __forceinline__ void stV(unsigned short* Vt, const bf16x8 r[4], int tid) {
#pragma unroll
  for (int it = 0; it < 4; it++) {
    int idx = tid + it * 256;
    int d = idx >> 3, sc = idx & 7;
    *(bf16x8*)(&Vt[d * VT_STRIDE + sc * 8]) = r[it];
  }
}

// Fused A/B QK^T: one K-fragment ds_read feeds both q-tiles' MFMAs.
__device__ __forceinline__ void qk4_pair(f32x4 sfrA[4], f32x4 sfrB[4], const unsigned short* Ks,
                                         const bf16x8 qfA[4], const bf16x8 qfB[4], bool doA,
                                         int l16, int quad) {
#pragma unroll
  for (int kt = 0; kt < 4; kt++) {
    f32x4 aA = {0.f, 0.f, 0.f, 0.f}, aB = {0.f, 0.f, 0.f, 0.f};
    const unsigned short* kp = &Ks[(kt * 16 + l16) * KS_STRIDE + quad * 8];
#pragma unroll
    for (int s = 0; s < 4; s++) {
      bf16x8 kf = *(const bf16x8*)(kp + s * 32);
      if (doA) aA = __builtin_amdgcn_mfma_f32_16x16x32_bf16(qfA[s], kf, aA, 0, 0, 0);
      aB = __builtin_amdgcn_mfma_f32_16x16x32_bf16(qfB[s], kf, aB, 0, 0, 0);
    }
    sfrA[kt] = aA;
    sfrB[kt] = aB;
  }
}
__device__ __forceinline__ void lacc(float l[4], const f32x4 sfr[4], float ss, bool diag,
                                     int j0, int qrb, int l16) {
  if (!diag) {
#pragma unroll
    for (int kt = 0; kt < 4; kt++)
#pragma unroll
      for (int r = 0; r < 4; r++) l[r] += __expf(fminf(sfr[kt][r] * ss, 80.0f));
  } else {
#pragma unroll
    for (int kt = 0; kt < 4; kt++) {
      const int key = j0 + kt * 16 + l16;
#pragma unroll
      for (int r = 0; r < 4; r++) {
        float e = __expf(fminf(sfr[kt][r] * ss, 80.0f));
        l[r] += (key <= qrb + r) ? e : 0.0f;
      }
    }
  }
}
__device__ __forceinline__ void pquant(unsigned short* Psb, const f32x4 sfr[4],
                                       const float il[4], float ss, bool diag, int j0,
                                       int qrb, int wave, int l16, int quad) {
  if (!diag) {
#pragma unroll
    for (int kt = 0; kt < 4; kt++)
#pragma unroll
      for (int r = 0; r < 4; r++) {
        float e = __expf(fminf(sfr[kt][r] * ss, 80.0f));
        float p = fminf(rintf(e * il[r]), 127.0f);
        Psb[(wave * 16 + quad * 4 + r) * PS_STRIDE + kt * 16 + l16] = f2bf(p);
      }
  } else {
#pragma unroll
    for (int kt = 0; kt < 4; kt++) {
      const int key = j0 + kt * 16 + l16;
#pragma unroll
      for (int r = 0; r < 4; r++) {
        float e = __expf(fminf(sfr[kt][r] * ss, 80.0f));
        float p = (key <= qrb + r) ? fminf(rintf(e * il[r]), 127.0f) : 0.0f;
        Psb[(wave * 16 + quad * 4 + r) * PS_STRIDE + kt * 16 + l16] = f2bf(p);
      }
    }
  }
}
// Fused A/B PV: one V-fragment ds_read feeds both q-tiles' MFMAs.
// Ps rows 0..63 = tile A, rows 64..127 = tile B; rows are wave-private (in-wave LDS order).
__device__ __forceinline__ void pvacc_pair(f32x4 ofA[8], f32x4 ofB[8], const unsigned short* Ps,
                                           const unsigned short* Vt, bool doA, int wave,
                                           int l16, int quad) {
  const unsigned short* ppA = &Ps[(wave * 16 + l16) * PS_STRIDE + quad * 8];
  const unsigned short* ppB = ppA + 64 * PS_STRIDE;
  bf16x8 pA0, pA1;
  if (doA) {
    pA0 = *(const bf16x8*)ppA;
    pA1 = *(const bf16x8*)(ppA + 32);
  }
  bf16x8 pB0 = *(const bf16x8*)ppB;
  bf16x8 pB1 = *(const bf16x8*)(ppB + 32);
#pragma unroll
  for (int n = 0; n < 8; n++) {
    const unsigned short* vp = &Vt[(n * 16 + l16) * VT_STRIDE + quad * 8];
    bf16x8 v0 = *(const bf16x8*)vp;
    bf16x8 v1 = *(const bf16x8*)(vp + 32);
    ofB[n] = __builtin_amdgcn_mfma_f32_16x16x32_bf16(pB0, v0, ofB[n], 0, 0, 0);
    ofB[n] = __builtin_amdgcn_mfma_f32_16x16x32_bf16(pB1, v1, ofB[n], 0, 0, 0);
    if (doA) {
      ofA[n] = __builtin_amdgcn_mfma_f32_16x16x32_bf16(pA0, v0, ofA[n], 0, 0, 0);
      ofA[n] = __builtin_amdgcn_mfma_f32_16x16x32_bf16(pA1, v1, ofA[n], 0, 0, 0);
    }
  }
}

__global__ __launch_bounds__(256, 2) void attn_mfma_kernel(const unsigned short* __restrict__ qb,
                                                           const unsigned short* __restrict__ kb,
                                                           const unsigned short* __restrict__ vbt,
                                                           float* __restrict__ ob,
                                                           unsigned int* __restrict__ slots) {
  __shared__ unsigned short Ks[TK * KS_STRIDE];
  __shared__ unsigned short Vt[HD * VT_STRIDE];
  __shared__ unsigned short Ps[128 * PS_STRIDE];  // A rows 0..63, B rows 64..127

  const int tid = threadIdx.x;
  const int wave = tid >> 6;
  const int lane = tid & 63;
  const int l16 = lane & 15;
  const int quad = lane >> 4;
  // XCD-group swizzle: id&7 selects (b,hk) so all 64 blocks sharing one K/V working
  // set (~1MB bf16) land on the same XCD's L2 (round-robin id%8 -> XCD).
  const int id = blockIdx.x;
  const int b = (id & 7) >> 2;
  const int hk = id & 3;
  const int j = id >> 3;          // 0..63
  const int h = hk * GROUPS + (j & 3);
  const int slot = j >> 2;        // 0..15
  const int q0A = slot * 64, ntA = slot + 1;
  const int q0B = (31 - slot) * 64, ntB = 32 - slot;

  const float s_q = slot_scale(slots, 5);
  const float s_k = slot_scale(slots, 6);
  const float s_v = slot_scale(slots, 7);
  const float ss = s_q * s_k / 11.313708498984761f;  // /sqrt(128)
  const float scale_p = 1.0f / 127.0f;
  const size_t vbase = ((size_t)(b * NKV + hk)) * HD * SEQ;

  bf16x8 qfA[4], qfB[4];
  {
    const unsigned short* qpA =
        qb + ((size_t)(b * SEQ + q0A + wave * 16 + l16) * NH + h) * HD + quad * 8;
    const unsigned short* qpB =
        qb + ((size_t)(b * SEQ + q0B + wave * 16 + l16) * NH + h) * HD + quad * 8;
#pragma unroll
    for (int s = 0; s < 4; s++) {
      qfA[s] = *(const bf16x8*)(qpA + s * 32);
      qfB[s] = *(const bf16x8*)(qpB + s * 32);
    }
  }
  const int qrbA = q0A + wave * 16 + quad * 4;
  const int qrbB = q0B + wave * 16 + quad * 4;

  // ---- Pass A: l sums for both q-tiles (fused K-fragment reads) ----
  float lA[4] = {0.f, 0.f, 0.f, 0.f}, lB[4] = {0.f, 0.f, 0.f, 0.f};
  bf16x8 kreg[4];
  ldK(kreg, kb, b, hk, 0, tid);
  for (int t = 0; t < ntB; t++) {
    const int j0 = t * TK;
    __syncthreads();
    stK(Ks, kreg, tid);
    if (t + 1 < ntB) ldK(kreg, kb, b, hk, (t + 1) * TK, tid);
    __syncthreads();
    const bool doA = (t < ntA);
    f32x4 sfrA[4], sfrB[4];
    qk4_pair(sfrA, sfrB, Ks, qfA, qfB, doA, l16, quad);
    if (doA) lacc(lA, sfrA, ss, t == ntA - 1, j0, qrbA, l16);
    lacc(lB, sfrB, ss, t == ntB - 1, j0, qrbB, l16);
  }
  float ilA[4], ilB[4];
#pragma unroll
  for (int r = 0; r < 4; r++) {
#pragma unroll
    for (int off = 1; off < 16; off <<= 1) {
      lA[r] += __shfl_xor(lA[r], off);
      lB[r] += __shfl_xor(lB[r], off);
    }
    ilA[r] = 127.0f / fmaxf(lA[r], 1e-30f);
    ilB[r] = 127.0f / fmaxf(lB[r], 1e-30f);
  }

  // ---- Pass B: recompute S, quantize P, PV for both q-tiles (fused K/V reads) ----
  f32x4 ofA[8], ofB[8];
#pragma unroll
  for (int n = 0; n < 8; n++) {
    ofA[n] = (f32x4){0.f, 0.f, 0.f, 0.f};
    ofB[n] = (f32x4){0.f, 0.f, 0.f, 0.f};
  }
  bf16x8 vreg[4];
  ldK(kreg, kb, b, hk, 0, tid);
  ldV(vreg, vbt, vbase, 0, tid);
  for (int t = 0; t < ntB; t++) {
    const int j0 = t * TK;
    __syncthreads();
    stK(Ks, kreg, tid);
    stV(Vt, vreg, tid);
    if (t + 1 < ntB) {
      ldK(kreg, kb, b, hk, (t + 1) * TK, tid);
      ldV(vreg, vbt, vbase, (t + 1) * TK, tid);
    }
    __syncthreads();
    const bool doA = (t < ntA);
    f32x4 sfrA[4], sfrB[4];
    qk4_pair(sfrA, sfrB, Ks, qfA, qfB, doA, l16, quad);
    if (doA) pquant(Ps, sfrA, ilA, ss, t == ntA - 1, j0, qrbA, wave, l16, quad);
    pquant(Ps + 64 * PS_STRIDE, sfrB, ilB, ss, t == ntB - 1, j0, qrbB, wave, l16, quad);
    pvacc_pair(ofA, ofB, Ps, Vt, doA, wave, l16, quad);
  }

  // ---- epilogue ----
  const float oscale = scale_p * s_v;
  float amax = 0.0f;
#pragma unroll
  for (int n = 0; n < 8; n++)
#pragma unroll
    for (int r = 0; r < 4; r++) {
      float vA = ofA[n][r] * oscale;
      float vB = ofB[n][r] * oscale;
      ob[((size_t)(b * SEQ + qrbA + r) * NH + h) * HD + n * 16 + l16] = vA;
      ob[((size_t)(b * SEQ + qrbB + r) * NH + h) * HD + n * 16 + l16] = vB;
      amax = fmaxf(amax, fmaxf(fabsf(vA), fabsf(vB)));
    }
  __syncthreads();
  block_amax_atomic(amax, &slots[8]);
}

extern "C" void kernel_launch(void* const* d_in, const int* in_sizes, int n_in,
                              void* d_out, int out_size, void* d_ws, size_t ws_size,
                              hipStream_t stream) {
  const float* hs = (const float*)d_in[0];
  const float* wq = (const float*)d_in[3];
  const float* wk = (const float*)d_in[4];
  const float* wv = (const float*)d_in[5];
  const float* wo = (const float*)d_in[6];
  float* out = (float*)d_out;

  unsigned int* slots = (unsigned int*)d_ws;
  char* p = (char*)d_ws + 256;
  unsigned short* hsq = (unsigned short*)p;  p += 2 * N_HS;  // dead after QKV GEMM
  unsigned short* wqq = (unsigned short*)p;  p += 2 * N_WQ;
  unsigned short* wkq = (unsigned short*)p;  p += 2 * N_WKV;
  unsigned short* wvq = (unsigned short*)p;  p += 2 * N_WKV;
  unsigned short* woq = (unsigned short*)p;  p += 2 * N_WO;
  float* kbuf = (float*)p;                   p += 4 * N_KV;
  float* vbuf = (float*)p;                   p += 4 * N_KV;
  unsigned short* qbf = (unsigned short*)p;  p += 2 * N_Q;
  unsigned short* kbf = (unsigned short*)p;  p += 2 * N_KV;
  unsigned short* vbt = (unsigned short*)p;  // transposed quantized V
  unsigned short* aobf = hsq;  // alias: hsq dead after QKV GEMM
  float* qbuf = out;           // fp32 q-proj output lives in d_out
  float* aobuf = out;          // fp32 attn output lives in d_out

  hipMemsetAsync(d_ws, 0, 256, stream);

  // slots: 0=x 1=wq 2=wk 3=wv 4=wo 5=q 6=k 7=v 8=ao
  absmax5_k<<<dim3(128, 5), 256, 0, stream>>>(hs, wq, wk, wv, wo, slots);
  quant5_k<<<dim3(128, 5), 256, 0, stream>>>(hs, wq, wk, wv, wo, slots, hsq, wqq, wkq, wvq, woq);

  const int M = BATCH * SEQ;
  gemm_qkv_k<<<dim3(24, M / 128), 256, 0, stream>>>(hsq, wqq, wkq, wvq, qbuf, kbuf, vbuf, slots);

  rope_kernel<<<(BATCH * SEQ * NH * (HD / 2)) / 256, 256, 0, stream>>>(qbuf, NH, slots + 5);
  rope_kernel<<<(BATCH * SEQ * NKV * (HD / 2)) / 256, 256, 0, stream>>>(kbuf, NKV, slots + 6);

  quant2_k<<<dim3(128, 2), 256, 0, stream>>>(qbuf, kbuf, slots, qbf, kbf);
  vtq_k<<<dim3(SEQ / 64, NKV, BATCH), 256, 0, stream>>>(vbuf, slots, vbt);

  attn_mfma_kernel<<<dim3(512, 1, 1), 256, 0, stream>>>(qbf, kbf, vbt, aobuf, slots);

  quant1_k<<<256, 256, 0, stream>>>(aobuf, N_Q / 4, slots + 8, aobf);

  gemm_o_k<<<dim3(HID / 128, M / 128), 256, 0, stream>>>(aobf, woq, out, slots);
}